// Round 18
// baseline (282.795 us; speedup 1.0000x reference)
//
#include <hip/hip_runtime.h>
#include <math.h>

#define NB 2
#define SEQ 3073
#define DIM 768
#define NH 12
#define DH 64
#define HHH 64
#define WWW 48
#define NPATCH 3072
#define QSCALE_L2E 0.18033688f   // 0.125 * log2(e); softmax in base 2
#define KSPLIT 1536              // split-0: 24 tiles; split-1: 25 (masked)

#define BHN (NB * NH)                 // 24
#define MROWS (NB * SEQ)              // 6146
#define MPAD 6272                     // 49 * 128
#define CNT (BHN * SEQ * DH)          // 4720128
#define VTSTRIDE 3136

typedef __attribute__((ext_vector_type(8))) short s8v;    // 8 x bf16 bits
typedef __attribute__((ext_vector_type(4))) float f4v;    // MFMA accumulator
typedef __attribute__((ext_vector_type(4))) ushort u4v;   // 4 x bf16 bits

#define MFMA16(a, b, c) __builtin_amdgcn_mfma_f32_16x16x32_bf16((a), (b), (c), 0, 0, 0)

__device__ __forceinline__ ushort f2bf(float f) {   // RTNE float -> bf16 bits
    unsigned x = __float_as_uint(f);
    return (ushort)((x + 0x7FFFu + ((x >> 16) & 1u)) >> 16);
}
__device__ __forceinline__ float bf2f(ushort u) {
    return __uint_as_float(((unsigned)u) << 16);
}
__device__ __forceinline__ unsigned cvt_pk_bf16(float a, float b) {
    unsigned r;   // r = {lo: bf16(a), hi: bf16(b)}
    asm("v_cvt_pk_bf16_f32 %0, %1, %2" : "=v"(r) : "v"(a), "v"(b));
    return r;
}
// async global->LDS, 16B per lane; LDS dest = uniform base + lane*16.
__device__ __forceinline__ void gl_lds16(const ushort* g, ushort* l) {
    __builtin_amdgcn_global_load_lds(
        (const __attribute__((address_space(1))) unsigned int*)g,
        (__attribute__((address_space(3))) unsigned int*)l, 16, 0, 0);
}

// swizzled LDS fragment read: [row][64] bf16 tile, byte ^= ((row&7)<<4)
__device__ __forceinline__ s8v ldsFrag(const ushort* base, int row, int half, int t) {
    int byte = (row * 128 + half * 64 + t * 16) ^ ((row & 7) << 4);
    return *(const s8v*)((const char*)base + byte);
}

// ---------------------------------------------------------------------------
// cast_bf16: fp32 -> bf16; zero-pads [n_in, 4*n_grp).
// ---------------------------------------------------------------------------
__global__ __launch_bounds__(256) void cast_bf16(const float* __restrict__ in,
                                                 ushort* __restrict__ out,
                                                 int n_in, int n_grp) {
    for (int g = blockIdx.x * 256 + threadIdx.x; g < n_grp; g += gridDim.x * 256) {
        int i0 = g * 4;
        float4 vv;
        if (i0 + 4 <= n_in) {
            vv = *(const float4*)(in + i0);
        } else {
            vv.x = (i0 + 0 < n_in) ? in[i0 + 0] : 0.f;
            vv.y = (i0 + 1 < n_in) ? in[i0 + 1] : 0.f;
            vv.z = (i0 + 2 < n_in) ? in[i0 + 2] : 0.f;
            vv.w = (i0 + 3 < n_in) ? in[i0 + 3] : 0.f;
        }
        u4v hv;
        hv[0] = f2bf(vv.x); hv[1] = f2bf(vv.y);
        hv[2] = f2bf(vv.z); hv[3] = f2bf(vv.w);
        *(u4v*)(out + i0) = hv;
    }
}

// ---------------------------------------------------------------------------
// Single-pass bf16 tile core: C[128x128] = A . B^T, K=768, 32 MFMA/tile,
// 32 KB LDS. Staging via global_load_lds: LINEAR LDS dest, INVERSE-swizzled
// global source (chunk c' = c ^ (r&7)); reads keep the XOR swizzle (m173).
// ---------------------------------------------------------------------------
__device__ __forceinline__ void mfma_tile_768_s1(const ushort* __restrict__ gA,
                                                 const ushort* __restrict__ gB,
                                                 ushort* Ah, ushort* Bh,
                                                 f4v acc[4][4]) {
    const int tid = threadIdx.x;
    const int lane = tid & 63;
    const int w = tid >> 6;
    const int lo = lane & 15, t = lane >> 4;
    const int wr = w >> 1, wc = w & 1;
    const int w4 = w * 4;                  // slot-group base for this wave

    for (int k0 = 0; k0 < DIM; k0 += 64) {
        __syncthreads();                   // prior reads done before overwrite
        #pragma unroll
        for (int i = 0; i < 4; ++i) {
            int s = (w4 + i) * 64 + lane;  // chunk id 0..1023
            int r = s >> 3, c = s & 7;     // row 0..127, 16B chunk 0..7
            int cp = c ^ (r & 7);          // inverse-swizzled source chunk
            size_t go = (size_t)r * DIM + k0 + cp * 8;
            int lb = (w4 + i) * 1024;      // linear LDS byte base (wave-uniform)
            gl_lds16(gA + go, (ushort*)((char*)Ah + lb));
            gl_lds16(gB + go, (ushort*)((char*)Bh + lb));
        }
        __syncthreads();                   // drains vmcnt (compiler-inserted)

        #pragma unroll
        for (int h = 0; h < 2; ++h) {
            s8v af[4];
            #pragma unroll
            for (int i = 0; i < 4; ++i)
                af[i] = ldsFrag(Ah, wr * 64 + i * 16 + lo, h, t);
            #pragma unroll
            for (int j = 0; j < 4; ++j) {
                s8v bf = ldsFrag(Bh, wc * 64 + j * 16 + lo, h, t);
                #pragma unroll
                for (int i = 0; i < 4; ++i)
                    acc[i][j] = MFMA16(af[i], bf, acc[i][j]);
            }
        }
    }
}

// ---------------------------------------------------------------------------
// QKV projection (single-pass bf16). Epilogue: q (bf16, *0.125*log2e),
// k (bf16), v, and V^T (vt[bh][d][kc]).
// ---------------------------------------------------------------------------
__global__ __launch_bounds__(256) void qkv_mfma(const ushort* __restrict__ xh,
                                                const ushort* __restrict__ wh,
                                                ushort* __restrict__ q_bf,
                                                ushort* __restrict__ k_bf,
                                                ushort* __restrict__ v_bf,
                                                ushort* __restrict__ vt) {
    __shared__ __align__(16) ushort Ah[8192], Bh[8192];   // 32 KB
    const int m0 = blockIdx.x * 128;
    const int nb = blockIdx.y;                  // 0..17
    f4v acc[4][4] = {};
    mfma_tile_768_s1(xh + (size_t)m0 * DIM,
                     wh + (size_t)nb * 128 * DIM, Ah, Bh, acc);

    const int tid = threadIdx.x;
    const int lane = tid & 63;
    const int w = tid >> 6;
    const int lo = lane & 15, t = lane >> 4;
    const int wr = w >> 1, wc = w & 1;
    const int which = nb / 6;                   // 0=q, 1=k, 2=v (uniform)
    const int rr0 = (nb % 6) * 128;

    #pragma unroll
    for (int i = 0; i < 4; ++i) {
        #pragma unroll
        for (int r = 0; r < 4; ++r) {
            int m = m0 + wr * 64 + i * 16 + t * 4 + r;
            if (m >= MROWS) continue;
            int bb = m / SEQ;
            int row = m - bb * SEQ;
            #pragma unroll
            for (int j = 0; j < 4; ++j) {
                int rr = rr0 + wc * 64 + j * 16 + lo;
                int hh = rr >> 6, dd = rr & 63;
                size_t base = ((size_t)(bb * NH + hh) * SEQ + row) * DH + dd;
                float val = acc[i][j][r];
                if (which == 0) {
                    q_bf[base] = f2bf(val * QSCALE_L2E);
                } else if (which == 1) {
                    k_bf[base] = f2bf(val);
                } else {
                    ushort vb = f2bf(val);
                    v_bf[base] = vb;
                    vt[((size_t)(bb * NH + hh) * DH + dd) * VTSTRIDE + row] = vb;
                }
            }
        }
    }
}

// ---------------------------------------------------------------------------
// Output projection (single-pass bf16) + bias -> fp32 out.
// ---------------------------------------------------------------------------
__global__ __launch_bounds__(256) void proj_mfma(const ushort* __restrict__ ah,
                                                 const ushort* __restrict__ pwh,
                                                 const float* __restrict__ bias,
                                                 float* __restrict__ out) {
    __shared__ __align__(16) ushort Ah[8192], Bh[8192];   // 32 KB
    const int m0 = blockIdx.x * 128;
    const int nb = blockIdx.y;                  // 0..5
    f4v acc[4][4] = {};
    mfma_tile_768_s1(ah + (size_t)m0 * DIM,
                     pwh + (size_t)nb * 128 * DIM, Ah, Bh, acc);

    const int tid = threadIdx.x;
    const int lane = tid & 63;
    const int w = tid >> 6;
    const int lo = lane & 15, t = lane >> 4;
    const int wr = w >> 1, wc = w & 1;

    #pragma unroll
    for (int i = 0; i < 4; ++i) {
        #pragma unroll
        for (int r = 0; r < 4; ++r) {
            int m = m0 + wr * 64 + i * 16 + t * 4 + r;
            if (m >= MROWS) continue;
            #pragma unroll
            for (int j = 0; j < 4; ++j) {
                int n = nb * 128 + wc * 64 + j * 16 + lo;
                out[(size_t)m * DIM + n] = acc[i][j][r] + bias[n];
            }
        }
    }
}

// ---------------------------------------------------------------------------
// MFMA flash attention v12: double-buffered K/V -> ONE barrier per iter.
// Iter n: compute from buf[ib]; prefetched regs for tile n+1 written to
// buf[ib^1] after compute; barrier. (Writes to buf[ib] only recur at iter
// n+1's end, after the barrier -> race-free.) Register-li, QBLK=64,
// split-K x2, no-max base-2 softmax, cvt_pk P-pack. LDS 40 KB.
// ---------------------------------------------------------------------------
__global__ __launch_bounds__(128, 2) void attn_mfma(const ushort* __restrict__ qh,
                                                    const ushort* __restrict__ kh,
                                                    const ushort* __restrict__ vt,
                                                    float* __restrict__ o0,
                                                    float* __restrict__ o1,
                                                    float* __restrict__ pli) {
    __shared__ __align__(16) ushort Kh[2][4096];   // 64 keys x 64 d, swizzled
    __shared__ __align__(16) ushort Vt[2][4096];   // 64 d x 64 kc, swizzled
    __shared__ __align__(16) ushort Pl[2][2048];   // per-wave 32x64 bf16, swizzled

    const int tid = threadIdx.x;     // 0..127
    const int w = tid >> 6;          // wave 0,1
    const int lane = tid & 63;
    const int lo = lane & 15;
    const int t = lane >> 4;
    const int bh = blockIdx.y;
    const int q0 = blockIdx.x * 64;
    const int z = blockIdx.z;
    const int kbeg = z * KSPLIT;
    const int kend = z ? SEQ : KSPLIT;

    // Q fragments for 2 row-groups (B-frag: row=lane&15, k=half*32+t*8+e)
    s8v qf0[2], qf1[2];
    #pragma unroll
    for (int g = 0; g < 2; ++g) {
        int qr = q0 + w * 32 + g * 16 + lo;
        if (qr > SEQ - 1) qr = SEQ - 1;
        const size_t qoff = ((size_t)bh * SEQ + qr) * DH + t * 8;
        qf0[g] = *(const s8v*)(qh + qoff);
        qf1[g] = *(const s8v*)(qh + qoff + 32);
    }

    // staging: thread covers tile row rr = tid>>1, 4 chunks at cc = (tid&1)*4
    const int rr = tid >> 1;              // 0..63
    const int cc = (tid & 1) * 4;         // 16B-chunk base (0 or 4)
    int sbyte[4];
    #pragma unroll
    for (int i = 0; i < 4; ++i)
        sbyte[i] = (rr * 128 + (cc + i) * 16) ^ ((rr & 7) << 4);
    const ushort* gk = kh + (size_t)bh * SEQ * DH;
    const ushort* gvb = vt + (size_t)bh * DH * VTSTRIDE;

    // prologue: prefetch tile kbeg, write to buf 0, sync
    s8v pkh[4], pvv[4];
    #pragma unroll
    for (int i = 0; i < 4; ++i) {
        pkh[i] = *(const s8v*)(gk + (size_t)(kbeg + rr) * DH + (cc + i) * 8);
        pvv[i] = *(const s8v*)(gvb + (size_t)rr * VTSTRIDE + kbeg + (cc + i) * 8);
    }
    #pragma unroll
    for (int i = 0; i < 4; ++i) {
        *(s8v*)((char*)Kh[0] + sbyte[i]) = pkh[i];
        *(s8v*)((char*)Vt[0] + sbyte[i]) = pvv[i];
    }
    __syncthreads();

    f4v o[2][4] = {};                // o[g][dt]
    float lp[2] = {0.f, 0.f};        // per-lane li partials
    int ib = 0;

    for (int k0 = kbeg; k0 < kend; k0 += 64, ib ^= 1) {
        const int kn = k0 + 64;
        const bool more = (kn < kend);
        // issue next-tile loads; they fly under this tile's compute
        if (more) {
            #pragma unroll
            for (int i = 0; i < 4; ++i) {
                pkh[i] = *(const s8v*)(gk + (size_t)(kn + rr) * DH + (cc + i) * 8);
                pvv[i] = *(const s8v*)(gvb + (size_t)rr * VTSTRIDE + kn + (cc + i) * 8);
            }
        }

        // S^T = K.Q^T (swapped operands, single-pass bf16) from buf[ib].
        // sv[g][tc][r] = score[q=lo][kc = k0 + 16*tc + 4*t + r]  (base-2)
        f4v sv[2][4];
        __builtin_amdgcn_s_setprio(1);
        #pragma unroll
        for (int tc = 0; tc < 4; ++tc) {
            int row = tc * 16 + lo;
            s8v b0 = ldsFrag(Kh[ib], row, 0, t);
            s8v b1 = ldsFrag(Kh[ib], row, 1, t);
            #pragma unroll
            for (int g = 0; g < 2; ++g) {
                f4v a = {0.f, 0.f, 0.f, 0.f};
                a = MFMA16(b0, qf0[g], a);
                a = MFMA16(b1, qf1[g], a);
                sv[g][tc] = a;
            }
        }
        __builtin_amdgcn_s_setprio(0);

        // mask invalid keys (kc is the row dim: kc = k0+16tc+4t+r)
        if (k0 + 64 > SEQ) {
            #pragma unroll
            for (int tc = 0; tc < 4; ++tc)
                #pragma unroll
                for (int r = 0; r < 4; ++r)
                    if (k0 + tc * 16 + 4 * t + r >= SEQ) {
                        sv[0][tc][r] = -1e30f;
                        sv[1][tc][r] = -1e30f;
                    }
        }

        // p = 2^s -> bf16 via cvt_pk; accumulate register li; b64 P-writes
        #pragma unroll
        for (int g = 0; g < 2; ++g) {
            int prow = g * 16 + lo;
            int rb = prow * 128 + t * 8;
            #pragma unroll
            for (int tc = 0; tc < 4; ++tc) {
                float p0 = exp2f(sv[g][tc][0]);
                float p1 = exp2f(sv[g][tc][1]);
                float p2 = exp2f(sv[g][tc][2]);
                float p3 = exp2f(sv[g][tc][3]);
                lp[g] += (p0 + p1) + (p2 + p3);
                uint2 pk;
                pk.x = cvt_pk_bf16(p0, p1);
                pk.y = cvt_pk_bf16(p2, p3);
                int byte = (rb + tc * 32) ^ ((lo & 7) << 4);
                *(uint2*)((char*)Pl[w] + byte) = pk;
            }
        }

        // O += P.V from buf[ib]  (V frags shared by both groups)
        s8v pf0[2], pf1[2];
        #pragma unroll
        for (int g = 0; g < 2; ++g) {
            pf0[g] = ldsFrag(Pl[w], g * 16 + lo, 0, t);
            pf1[g] = ldsFrag(Pl[w], g * 16 + lo, 1, t);
        }
        __builtin_amdgcn_s_setprio(1);
        #pragma unroll
        for (int dt = 0; dt < 4; ++dt) {
            s8v v0 = ldsFrag(Vt[ib], dt * 16 + lo, 0, t);
            s8v v1 = ldsFrag(Vt[ib], dt * 16 + lo, 1, t);
            #pragma unroll
            for (int g = 0; g < 2; ++g) {
                o[g][dt] = MFMA16(pf0[g], v0, o[g][dt]);
                o[g][dt] = MFMA16(pf1[g], v1, o[g][dt]);
            }
        }
        __builtin_amdgcn_s_setprio(0);

        // write next tile into the other buffer, then the ONE barrier
        if (more) {
            #pragma unroll
            for (int i = 0; i < 4; ++i) {
                *(s8v*)((char*)Kh[ib ^ 1] + sbyte[i]) = pkh[i];
                *(s8v*)((char*)Vt[ib ^ 1] + sbyte[i]) = pvv[i];
            }
        }
        __syncthreads();
    }

    // reduce li across the 4 t-subgroups (lanes lo, lo+16, lo+32, lo+48
    // share q-row g*16+lo)
    #pragma unroll
    for (int g = 0; g < 2; ++g) {
        lp[g] += __shfl_xor(lp[g], 16);
        lp[g] += __shfl_xor(lp[g], 32);
    }

    // epilogue: write UNNORMALIZED o + li partial for this split
    const int b = bh / NH;
    const int h = bh - b * NH;
    float* obase = z ? o1 : o0;
    float* lbase = pli + (size_t)z * BHN * SEQ;
    #pragma unroll
    for (int g = 0; g < 2; ++g) {
        if (t == 0) {
            int row = q0 + w * 32 + g * 16 + lo;
            if (row < SEQ)
                lbase[(size_t)bh * SEQ + row] = lp[g];
        }
        #pragma unroll
        for (int r = 0; r < 4; ++r) {
            int row = q0 + w * 32 + g * 16 + t * 4 + r;
            if (row >= SEQ) continue;
            #pragma unroll
            for (int dt = 0; dt < 4; ++dt)
                obase[((size_t)(b * SEQ + row)) * DIM + h * DH + dt * 16 + lo] =
                    o[g][dt][r];
        }
    }
}

// ---------------------------------------------------------------------------
// Depthwise 3x3 conv positional embedding -> pe buffer (bf16). Row 0 (cls)
// is never written; combine treats it as zero.
// ---------------------------------------------------------------------------
__global__ __launch_bounds__(256) void conv_pe(const ushort* __restrict__ v,
                                               const float* __restrict__ cw,
                                               const float* __restrict__ cb,
                                               ushort* __restrict__ pe) {
    const int tid = threadIdx.x;
    const int c = tid & 63;
    const int tl = tid >> 6;
    const int blk = blockIdx.x;
    const int bh = blk / 768;
    const int pb = blk - bh * 768;
    const int p = pb * 4 + tl;
    const int y = p / WWW;
    const int x0 = p - y * WWW;

    const ushort* vb = v + (size_t)bh * SEQ * DH;
    float acc = cb[c];
    #pragma unroll
    for (int dy = -1; dy <= 1; ++dy) {
        int yy = y + dy;
        if (yy < 0 || yy >= HHH) continue;
        #pragma unroll
        for (int dx = -1; dx <= 1; ++dx) {
            int xx = x0 + dx;
            if (xx < 0 || xx >= WWW) continue;
            acc = fmaf(bf2f(vb[(size_t)(1 + yy * WWW + xx) * DH + c]),
                       cw[c * 9 + (dy + 1) * 3 + (dx + 1)], acc);
        }
    }
    const int b = bh / NH;
    const int h = bh - b * NH;
    pe[((size_t)(b * SEQ + 1 + p)) * DIM + h * DH + c] = f2bf(acc);
}

// ---------------------------------------------------------------------------
// Combine: ah = bf16( (o0 + o1) / (li0 + li1) + pe ) — fused normalize,
// positional-embedding add, and cast for the proj GEMM A operand.
// ---------------------------------------------------------------------------
__global__ __launch_bounds__(256) void combine_att(const float* __restrict__ o0,
                                                   const float* __restrict__ o1,
                                                   const float* __restrict__ pli,
                                                   const ushort* __restrict__ pe,
                                                   ushort* __restrict__ ah) {
    const int total = MROWS * DIM / 4;
    for (int i = blockIdx.x * 256 + threadIdx.x; i < total; i += gridDim.x * 256) {
        size_t e = (size_t)i * 4;
        int m = (int)(e / DIM);
        int d = (int)(e - (size_t)m * DIM);
        int b = m / SEQ;
        int row = m - b * SEQ;
        int h = d >> 6;
        size_t li = (size_t)(b * NH + h) * SEQ + row;
        float inv = 1.f / (pli[li] + pli[(size_t)BHN * SEQ + li]);
        float4 a = *(const float4*)(o0 + e);
        float4 p = *(const float4*)(o1 + e);
        float pv[4] = {0.f, 0.f, 0.f, 0.f};
        if (row > 0) {
            u4v pb = *(const u4v*)(pe + e);
            #pragma unroll
            for (int j = 0; j < 4; ++j) pv[j] = bf2f(pb[j]);
        }
        u4v rs;
        rs[0] = f2bf(fmaf(a.x + p.x, inv, pv[0]));
        rs[1] = f2bf(fmaf(a.y + p.y, inv, pv[1]));
        rs[2] = f2bf(fmaf(a.z + p.z, inv, pv[2]));
        rs[3] = f2bf(fmaf(a.w + p.w, inv, pv[3]));
        *(u4v*)(ah + e) = rs;
    }
}

// ---------------------------------------------------------------------------
extern "C" void kernel_launch(void* const* d_in, const int* in_sizes, int n_in,
                              void* d_out, int out_size, void* d_ws, size_t ws_size,
                              hipStream_t stream) {
    const float* x      = (const float*)d_in[0];
    const float* qkv_w  = (const float*)d_in[1];
    const float* proj_w = (const float*)d_in[2];
    const float* proj_b = (const float*)d_in[3];
    const float* conv_w = (const float*)d_in[4];
    const float* conv_b = (const float*)d_in[5];
    float* out = (float*)d_out;

    ushort* ws = (ushort*)d_ws;
    size_t o = 0;
    ushort* xh  = ws + o; o += (size_t)MPAD * DIM;    // 4,816,896
    o += (size_t)MPAD * DIM;                          // reserved (po1 overlay)
    ushort* wh  = ws + o; o += (size_t)2304 * DIM;    // 1,769,472
    ushort* pwh = ws + o; o += (size_t)DIM * DIM;     // 589,824
    ushort* q_bf = ws + o; o += CNT;
    ushort* k_bf = ws + o; o += CNT;    // K tail over-reads land in v_bf (in-ws, safe)
    ushort* v_bf = ws + o; o += CNT;
    ushort* vtb  = ws + o; o += (size_t)BHN * DH * VTSTRIDE;   // 4,816,896
    float*  o0   = (float*)(ws + o);    // unnormalized split-0 O, fp32
    // Overlays (all consumers strictly after producers on the stream):
    // po1 over xh+reserved (dead after qkv); pli after po1 (tail spills into
    // wh, dead after qkv; pwh untouched); pe over vtb (dead after attn);
    // ah over q_bf (dead after attn; MPAD tail spills into k_bf, also dead).
    float*  po1 = (float*)ws;
    float*  pli = (float*)(ws + (size_t)MROWS * DIM * 2);
    ushort* pe  = vtb;
    ushort* ah  = q_bf;

    cast_bf16<<<2048, 256, 0, stream>>>(x, xh, MROWS * DIM, MPAD * DIM / 4);
    cast_bf16<<<1024, 256, 0, stream>>>(qkv_w, wh, 2304 * DIM, 2304 * DIM / 4);
    cast_bf16<<<512, 256, 0, stream>>>(proj_w, pwh, DIM * DIM, DIM * DIM / 4);

    qkv_mfma<<<dim3(49, 18), 256, 0, stream>>>(xh, wh, q_bf, k_bf, v_bf, vtb);
    attn_mfma<<<dim3(49, BHN, 2), 128, 0, stream>>>(q_bf, k_bf, vtb, o0, po1, pli);
    conv_pe<<<BHN * (NPATCH / 4), 256, 0, stream>>>(v_bf, conv_w, conv_b, pe);
    combine_att<<<2048, 256, 0, stream>>>(o0, po1, pli, pe, ah);
    proj_mfma<<<dim3(49, 6), 256, 0, stream>>>(ah, pwh, proj_b, out);
}

// Round 19
// 245.637 us; speedup vs baseline: 1.1513x; 1.1513x over previous
//
#include <hip/hip_runtime.h>
#include <math.h>

#define NB 2
#define SEQ 3073
#define DIM 768
#define NH 12
#define DH 64
#define HHH 64
#define WWW 48
#define NPATCH 3072
#define QSCALE_L2E 0.18033688f   // 0.125 * log2(e); softmax in base 2
#define KSPLIT 1536              // split-0: 24 tiles; split-1: 25 (masked)

#define BHN (NB * NH)                 // 24
#define MROWS (NB * SEQ)              // 6146
#define MPAD 6272                     // 49 * 128
#define CNT (BHN * SEQ * DH)          // 4720128
#define VTSTRIDE 3136

typedef __attribute__((ext_vector_type(8))) short s8v;    // 8 x bf16 bits
typedef __attribute__((ext_vector_type(4))) float f4v;    // MFMA accumulator
typedef __attribute__((ext_vector_type(4))) ushort u4v;   // 4 x bf16 bits

#define MFMA16(a, b, c) __builtin_amdgcn_mfma_f32_16x16x32_bf16((a), (b), (c), 0, 0, 0)

__device__ __forceinline__ ushort f2bf(float f) {   // RTNE float -> bf16 bits
    unsigned x = __float_as_uint(f);
    return (ushort)((x + 0x7FFFu + ((x >> 16) & 1u)) >> 16);
}
__device__ __forceinline__ float bf2f(ushort u) {
    return __uint_as_float(((unsigned)u) << 16);
}
__device__ __forceinline__ unsigned cvt_pk_bf16(float a, float b) {
    unsigned r;   // r = {lo: bf16(a), hi: bf16(b)}
    asm("v_cvt_pk_bf16_f32 %0, %1, %2" : "=v"(r) : "v"(a), "v"(b));
    return r;
}
// async global->LDS, 16B per lane; LDS dest = uniform base + lane*16.
__device__ __forceinline__ void gl_lds16(const ushort* g, ushort* l) {
    __builtin_amdgcn_global_load_lds(
        (const __attribute__((address_space(1))) unsigned int*)g,
        (__attribute__((address_space(3))) unsigned int*)l, 16, 0, 0);
}

// swizzled LDS fragment read: [row][64] bf16 tile, byte ^= ((row&7)<<4)
__device__ __forceinline__ s8v ldsFrag(const ushort* base, int row, int half, int t) {
    int byte = (row * 128 + half * 64 + t * 16) ^ ((row & 7) << 4);
    return *(const s8v*)((const char*)base + byte);
}

// ---------------------------------------------------------------------------
// cast_bf16: fp32 -> bf16; zero-pads [n_in, 4*n_grp).
// ---------------------------------------------------------------------------
__global__ __launch_bounds__(256) void cast_bf16(const float* __restrict__ in,
                                                 ushort* __restrict__ out,
                                                 int n_in, int n_grp) {
    for (int g = blockIdx.x * 256 + threadIdx.x; g < n_grp; g += gridDim.x * 256) {
        int i0 = g * 4;
        float4 vv;
        if (i0 + 4 <= n_in) {
            vv = *(const float4*)(in + i0);
        } else {
            vv.x = (i0 + 0 < n_in) ? in[i0 + 0] : 0.f;
            vv.y = (i0 + 1 < n_in) ? in[i0 + 1] : 0.f;
            vv.z = (i0 + 2 < n_in) ? in[i0 + 2] : 0.f;
            vv.w = (i0 + 3 < n_in) ? in[i0 + 3] : 0.f;
        }
        u4v hv;
        hv[0] = f2bf(vv.x); hv[1] = f2bf(vv.y);
        hv[2] = f2bf(vv.z); hv[3] = f2bf(vv.w);
        *(u4v*)(out + i0) = hv;
    }
}

// ---------------------------------------------------------------------------
// Single-pass bf16 tile core: C[128x128] = A . B^T, K=768, 32 MFMA/tile,
// 32 KB LDS. Staging via global_load_lds: LINEAR LDS dest, INVERSE-swizzled
// global source (chunk c' = c ^ (r&7)); reads keep the XOR swizzle (m173).
// ---------------------------------------------------------------------------
__device__ __forceinline__ void mfma_tile_768_s1(const ushort* __restrict__ gA,
                                                 const ushort* __restrict__ gB,
                                                 ushort* Ah, ushort* Bh,
                                                 f4v acc[4][4]) {
    const int tid = threadIdx.x;
    const int lane = tid & 63;
    const int w = tid >> 6;
    const int lo = lane & 15, t = lane >> 4;
    const int wr = w >> 1, wc = w & 1;
    const int w4 = w * 4;                  // slot-group base for this wave

    for (int k0 = 0; k0 < DIM; k0 += 64) {
        __syncthreads();                   // prior reads done before overwrite
        #pragma unroll
        for (int i = 0; i < 4; ++i) {
            int s = (w4 + i) * 64 + lane;  // chunk id 0..1023
            int r = s >> 3, c = s & 7;     // row 0..127, 16B chunk 0..7
            int cp = c ^ (r & 7);          // inverse-swizzled source chunk
            size_t go = (size_t)r * DIM + k0 + cp * 8;
            int lb = (w4 + i) * 1024;      // linear LDS byte base (wave-uniform)
            gl_lds16(gA + go, (ushort*)((char*)Ah + lb));
            gl_lds16(gB + go, (ushort*)((char*)Bh + lb));
        }
        __syncthreads();                   // drains vmcnt (compiler-inserted)

        #pragma unroll
        for (int h = 0; h < 2; ++h) {
            s8v af[4];
            #pragma unroll
            for (int i = 0; i < 4; ++i)
                af[i] = ldsFrag(Ah, wr * 64 + i * 16 + lo, h, t);
            #pragma unroll
            for (int j = 0; j < 4; ++j) {
                s8v bf = ldsFrag(Bh, wc * 64 + j * 16 + lo, h, t);
                #pragma unroll
                for (int i = 0; i < 4; ++i)
                    acc[i][j] = MFMA16(af[i], bf, acc[i][j]);
            }
        }
    }
}

// ---------------------------------------------------------------------------
// QKV projection (single-pass bf16). Epilogue: q (bf16, *0.125*log2e),
// k (bf16), v, and V^T (vt[bh][d][kc]).
// ---------------------------------------------------------------------------
__global__ __launch_bounds__(256) void qkv_mfma(const ushort* __restrict__ xh,
                                                const ushort* __restrict__ wh,
                                                ushort* __restrict__ q_bf,
                                                ushort* __restrict__ k_bf,
                                                ushort* __restrict__ v_bf,
                                                ushort* __restrict__ vt) {
    __shared__ __align__(16) ushort Ah[8192], Bh[8192];   // 32 KB
    const int m0 = blockIdx.x * 128;
    const int nb = blockIdx.y;                  // 0..17
    f4v acc[4][4] = {};
    mfma_tile_768_s1(xh + (size_t)m0 * DIM,
                     wh + (size_t)nb * 128 * DIM, Ah, Bh, acc);

    const int tid = threadIdx.x;
    const int lane = tid & 63;
    const int w = tid >> 6;
    const int lo = lane & 15, t = lane >> 4;
    const int wr = w >> 1, wc = w & 1;
    const int which = nb / 6;                   // 0=q, 1=k, 2=v (uniform)
    const int rr0 = (nb % 6) * 128;

    #pragma unroll
    for (int i = 0; i < 4; ++i) {
        #pragma unroll
        for (int r = 0; r < 4; ++r) {
            int m = m0 + wr * 64 + i * 16 + t * 4 + r;
            if (m >= MROWS) continue;
            int bb = m / SEQ;
            int row = m - bb * SEQ;
            #pragma unroll
            for (int j = 0; j < 4; ++j) {
                int rr = rr0 + wc * 64 + j * 16 + lo;
                int hh = rr >> 6, dd = rr & 63;
                size_t base = ((size_t)(bb * NH + hh) * SEQ + row) * DH + dd;
                float val = acc[i][j][r];
                if (which == 0) {
                    q_bf[base] = f2bf(val * QSCALE_L2E);
                } else if (which == 1) {
                    k_bf[base] = f2bf(val);
                } else {
                    ushort vb = f2bf(val);
                    v_bf[base] = vb;
                    vt[((size_t)(bb * NH + hh) * DH + dd) * VTSTRIDE + row] = vb;
                }
            }
        }
    }
}

// ---------------------------------------------------------------------------
// Output projection (single-pass bf16) + bias -> fp32 out.
// ---------------------------------------------------------------------------
__global__ __launch_bounds__(256) void proj_mfma(const ushort* __restrict__ ah,
                                                 const ushort* __restrict__ pwh,
                                                 const float* __restrict__ bias,
                                                 float* __restrict__ out) {
    __shared__ __align__(16) ushort Ah[8192], Bh[8192];   // 32 KB
    const int m0 = blockIdx.x * 128;
    const int nb = blockIdx.y;                  // 0..5
    f4v acc[4][4] = {};
    mfma_tile_768_s1(ah + (size_t)m0 * DIM,
                     pwh + (size_t)nb * 128 * DIM, Ah, Bh, acc);

    const int tid = threadIdx.x;
    const int lane = tid & 63;
    const int w = tid >> 6;
    const int lo = lane & 15, t = lane >> 4;
    const int wr = w >> 1, wc = w & 1;

    #pragma unroll
    for (int i = 0; i < 4; ++i) {
        #pragma unroll
        for (int r = 0; r < 4; ++r) {
            int m = m0 + wr * 64 + i * 16 + t * 4 + r;
            if (m >= MROWS) continue;
            #pragma unroll
            for (int j = 0; j < 4; ++j) {
                int n = nb * 128 + wc * 64 + j * 16 + lo;
                out[(size_t)m * DIM + n] = acc[i][j][r] + bias[n];
            }
        }
    }
}

// ---------------------------------------------------------------------------
// MFMA flash attention v8 (verified 126 us): split-K x2, no-max softmax,
// unnormalized partials, reg-staged K/V with T14 prefetch, cvt_pk P-pack,
// li via ones-row in Vt (dt=4 column 0). LDS 26.6 KB.
// ---------------------------------------------------------------------------
__global__ __launch_bounds__(128, 2) void attn_mfma(const ushort* __restrict__ qh,
                                                    const ushort* __restrict__ kh,
                                                    const ushort* __restrict__ vt,
                                                    float* __restrict__ o0,
                                                    float* __restrict__ o1,
                                                    float* __restrict__ pli) {
    __shared__ __align__(16) ushort Kh[4096];   // 64 keys x 64 d, swizzled
    __shared__ __align__(16) ushort Vt[5120];   // 80 rows x 64 kc (64=ones, 65-79=0)
    __shared__ __align__(16) ushort Pl[2][2048];// per-wave 32 x 64 bf16, swizzled

    const int tid = threadIdx.x;     // 0..127
    const int w = tid >> 6;          // wave 0,1
    const int lane = tid & 63;
    const int lo = lane & 15;
    const int t = lane >> 4;
    const int bh = blockIdx.y;
    const int q0 = blockIdx.x * 64;
    const int z = blockIdx.z;
    const int kbeg = z * KSPLIT;
    const int kend = z ? SEQ : KSPLIT;

    // init Vt rows 64..79 once (row 64 = bf16 1.0, rest 0)
    {
        int rr = 64 + (tid >> 3);
        int col = (tid & 7) * 8;
        int byte = (rr * 128 + col * 2) ^ ((rr & 7) << 4);
        short v = (rr == 64) ? (short)0x3F80 : (short)0;
        s8v ones = {v, v, v, v, v, v, v, v};
        *(s8v*)((char*)Vt + byte) = ones;
    }

    // Q fragments for 2 row-groups (B-frag: row=lane&15, k=half*32+t*8+e)
    s8v qf0[2], qf1[2];
    #pragma unroll
    for (int g = 0; g < 2; ++g) {
        int qr = q0 + w * 32 + g * 16 + lo;
        if (qr > SEQ - 1) qr = SEQ - 1;
        const size_t qoff = ((size_t)bh * SEQ + qr) * DH + t * 8;
        qf0[g] = *(const s8v*)(qh + qoff);
        qf1[g] = *(const s8v*)(qh + qoff + 32);
    }

    // staging: thread covers tile row rr = tid>>1, 4 chunks at cc = (tid&1)*4
    const int rr = tid >> 1;              // 0..63
    const int cc = (tid & 1) * 4;         // 16B-chunk base (0 or 4)
    int sbyte[4];
    #pragma unroll
    for (int i = 0; i < 4; ++i)
        sbyte[i] = (rr * 128 + (cc + i) * 16) ^ ((rr & 7) << 4);
    const ushort* gk = kh + (size_t)bh * SEQ * DH;
    const ushort* gvb = vt + (size_t)bh * DH * VTSTRIDE;

    // prefetch first tile of this split (T14 issue-early)
    s8v pkh[4], pvv[4];
    #pragma unroll
    for (int i = 0; i < 4; ++i) {
        pkh[i] = *(const s8v*)(gk + (size_t)(kbeg + rr) * DH + (cc + i) * 8);
        pvv[i] = *(const s8v*)(gvb + (size_t)rr * VTSTRIDE + kbeg + (cc + i) * 8);
    }

    f4v o[2][5] = {};                // o[g][dt]; dt=4 is the li (ones) column

    for (int k0 = kbeg; k0 < kend; k0 += 64) {
        // write prefetched tile -> LDS
        #pragma unroll
        for (int i = 0; i < 4; ++i) {
            *(s8v*)((char*)Kh + sbyte[i]) = pkh[i];
            *(s8v*)((char*)Vt + sbyte[i]) = pvv[i];
        }
        __syncthreads();

        // issue next-tile loads; they fly under this tile's compute
        const int kn = k0 + 64;
        if (kn < SEQ) {
            #pragma unroll
            for (int i = 0; i < 4; ++i) {
                pkh[i] = *(const s8v*)(gk + (size_t)(kn + rr) * DH + (cc + i) * 8);
                pvv[i] = *(const s8v*)(gvb + (size_t)rr * VTSTRIDE + kn + (cc + i) * 8);
            }
        }

        // S^T = K.Q^T (swapped operands, single-pass bf16).
        // sv[g][tc][r] = score[q=lo][kc = k0 + 16*tc + 4*t + r]  (base-2)
        f4v sv[2][4];
        __builtin_amdgcn_s_setprio(1);
        #pragma unroll
        for (int tc = 0; tc < 4; ++tc) {
            int row = tc * 16 + lo;
            s8v b0 = ldsFrag(Kh, row, 0, t);
            s8v b1 = ldsFrag(Kh, row, 1, t);
            #pragma unroll
            for (int g = 0; g < 2; ++g) {
                f4v a = {0.f, 0.f, 0.f, 0.f};
                a = MFMA16(b0, qf0[g], a);
                a = MFMA16(b1, qf1[g], a);
                sv[g][tc] = a;
            }
        }
        __builtin_amdgcn_s_setprio(0);

        // mask invalid keys (kc is the row dim: kc = k0+16tc+4t+r)
        if (k0 + 64 > SEQ) {
            #pragma unroll
            for (int tc = 0; tc < 4; ++tc)
                #pragma unroll
                for (int r = 0; r < 4; ++r)
                    if (k0 + tc * 16 + 4 * t + r >= SEQ) {
                        sv[0][tc][r] = -1e30f;
                        sv[1][tc][r] = -1e30f;
                    }
        }

        // p = 2^s -> bf16 via v_cvt_pk_bf16_f32; one b64 write per (g,tc)
        #pragma unroll
        for (int g = 0; g < 2; ++g) {
            int prow = g * 16 + lo;
            int rb = prow * 128 + t * 8;
            #pragma unroll
            for (int tc = 0; tc < 4; ++tc) {
                float p0 = exp2f(sv[g][tc][0]);
                float p1 = exp2f(sv[g][tc][1]);
                float p2 = exp2f(sv[g][tc][2]);
                float p3 = exp2f(sv[g][tc][3]);
                uint2 pk;
                pk.x = cvt_pk_bf16(p0, p1);
                pk.y = cvt_pk_bf16(p2, p3);
                int byte = (rb + tc * 32) ^ ((lo & 7) << 4);
                *(uint2*)((char*)Pl[w] + byte) = pk;
            }
        }

        // O += P.V  (dt=4: ones row accumulates li). V frags shared by groups.
        s8v pf0[2], pf1[2];
        #pragma unroll
        for (int g = 0; g < 2; ++g) {
            pf0[g] = ldsFrag(Pl[w], g * 16 + lo, 0, t);
            pf1[g] = ldsFrag(Pl[w], g * 16 + lo, 1, t);
        }
        __builtin_amdgcn_s_setprio(1);
        #pragma unroll
        for (int dt = 0; dt < 5; ++dt) {
            s8v v0 = ldsFrag(Vt, dt * 16 + lo, 0, t);
            s8v v1 = ldsFrag(Vt, dt * 16 + lo, 1, t);
            #pragma unroll
            for (int g = 0; g < 2; ++g) {
                o[g][dt] = MFMA16(pf0[g], v0, o[g][dt]);
                o[g][dt] = MFMA16(pf1[g], v1, o[g][dt]);
            }
        }
        __builtin_amdgcn_s_setprio(0);

        __syncthreads();   // all waves done reading this tile's LDS
    }

    // epilogue: write UNNORMALIZED o + li partial for this split
    const int b = bh / NH;
    const int h = bh - b * NH;
    float* obase = z ? o1 : o0;
    float* lbase = pli + (size_t)z * BHN * SEQ;
    #pragma unroll
    for (int g = 0; g < 2; ++g) {
        #pragma unroll
        for (int r = 0; r < 4; ++r) {
            int row = q0 + w * 32 + g * 16 + t * 4 + r;
            if (row >= SEQ) continue;
            if (lo == 0)
                lbase[(size_t)bh * SEQ + row] = o[g][4][r];
            #pragma unroll
            for (int dt = 0; dt < 4; ++dt)
                obase[((size_t)(b * SEQ + row)) * DIM + h * DH + dt * 16 + lo] =
                    o[g][dt][r];
        }
    }
}

// ---------------------------------------------------------------------------
// Depthwise 3x3 conv positional embedding -> pe buffer (bf16). Row 0 (cls)
// is never written; combine treats it as zero.
// ---------------------------------------------------------------------------
__global__ __launch_bounds__(256) void conv_pe(const ushort* __restrict__ v,
                                               const float* __restrict__ cw,
                                               const float* __restrict__ cb,
                                               ushort* __restrict__ pe) {
    const int tid = threadIdx.x;
    const int c = tid & 63;
    const int tl = tid >> 6;
    const int blk = blockIdx.x;
    const int bh = blk / 768;
    const int pb = blk - bh * 768;
    const int p = pb * 4 + tl;
    const int y = p / WWW;
    const int x0 = p - y * WWW;

    const ushort* vb = v + (size_t)bh * SEQ * DH;
    float acc = cb[c];
    #pragma unroll
    for (int dy = -1; dy <= 1; ++dy) {
        int yy = y + dy;
        if (yy < 0 || yy >= HHH) continue;
        #pragma unroll
        for (int dx = -1; dx <= 1; ++dx) {
            int xx = x0 + dx;
            if (xx < 0 || xx >= WWW) continue;
            acc = fmaf(bf2f(vb[(size_t)(1 + yy * WWW + xx) * DH + c]),
                       cw[c * 9 + (dy + 1) * 3 + (dx + 1)], acc);
        }
    }
    const int b = bh / NH;
    const int h = bh - b * NH;
    pe[((size_t)(b * SEQ + 1 + p)) * DIM + h * DH + c] = f2bf(acc);
}

// ---------------------------------------------------------------------------
// Combine: ah = bf16( (o0 + o1) / (li0 + li1) + pe ) — fused normalize,
// positional-embedding add, and cast for the proj GEMM A operand.
// ---------------------------------------------------------------------------
__global__ __launch_bounds__(256) void combine_att(const float* __restrict__ o0,
                                                   const float* __restrict__ o1,
                                                   const float* __restrict__ pli,
                                                   const ushort* __restrict__ pe,
                                                   ushort* __restrict__ ah) {
    const int total = MROWS * DIM / 4;
    for (int i = blockIdx.x * 256 + threadIdx.x; i < total; i += gridDim.x * 256) {
        size_t e = (size_t)i * 4;
        int m = (int)(e / DIM);
        int d = (int)(e - (size_t)m * DIM);
        int b = m / SEQ;
        int row = m - b * SEQ;
        int h = d >> 6;
        size_t li = (size_t)(b * NH + h) * SEQ + row;
        float inv = 1.f / (pli[li] + pli[(size_t)BHN * SEQ + li]);
        float4 a = *(const float4*)(o0 + e);
        float4 p = *(const float4*)(o1 + e);
        float pv[4] = {0.f, 0.f, 0.f, 0.f};
        if (row > 0) {
            u4v pb = *(const u4v*)(pe + e);
            #pragma unroll
            for (int j = 0; j < 4; ++j) pv[j] = bf2f(pb[j]);
        }
        u4v rs;
        rs[0] = f2bf(fmaf(a.x + p.x, inv, pv[0]));
        rs[1] = f2bf(fmaf(a.y + p.y, inv, pv[1]));
        rs[2] = f2bf(fmaf(a.z + p.z, inv, pv[2]));
        rs[3] = f2bf(fmaf(a.w + p.w, inv, pv[3]));
        *(u4v*)(ah + e) = rs;
    }
}

// ---------------------------------------------------------------------------
extern "C" void kernel_launch(void* const* d_in, const int* in_sizes, int n_in,
                              void* d_out, int out_size, void* d_ws, size_t ws_size,
                              hipStream_t stream) {
    const float* x      = (const float*)d_in[0];
    const float* qkv_w  = (const float*)d_in[1];
    const float* proj_w = (const float*)d_in[2];
    const float* proj_b = (const float*)d_in[3];
    const float* conv_w = (const float*)d_in[4];
    const float* conv_b = (const float*)d_in[5];
    float* out = (float*)d_out;

    ushort* ws = (ushort*)d_ws;
    size_t o = 0;
    ushort* xh  = ws + o; o += (size_t)MPAD * DIM;    // 4,816,896
    o += (size_t)MPAD * DIM;                          // reserved (po1 overlay)
    ushort* wh  = ws + o; o += (size_t)2304 * DIM;    // 1,769,472
    ushort* pwh = ws + o; o += (size_t)DIM * DIM;     // 589,824
    ushort* q_bf = ws + o; o += CNT;
    ushort* k_bf = ws + o; o += CNT;    // K tail over-reads land in v_bf (in-ws, safe)
    ushort* v_bf = ws + o; o += CNT;
    ushort* vtb  = ws + o; o += (size_t)BHN * DH * VTSTRIDE;   // 4,816,896
    float*  o0   = (float*)(ws + o);    // unnormalized split-0 O, fp32
    // Overlays (all consumers strictly after producers on the stream):
    // po1 over xh+reserved (dead after qkv); pli after po1 (tail spills into
    // wh, dead after qkv; pwh untouched); pe over vtb (dead after attn);
    // ah over q_bf (dead after attn; MPAD tail spills into k_bf, also dead).
    float*  po1 = (float*)ws;
    float*  pli = (float*)(ws + (size_t)MROWS * DIM * 2);
    ushort* pe  = vtb;
    ushort* ah  = q_bf;

    cast_bf16<<<2048, 256, 0, stream>>>(x, xh, MROWS * DIM, MPAD * DIM / 4);
    cast_bf16<<<1024, 256, 0, stream>>>(qkv_w, wh, 2304 * DIM, 2304 * DIM / 4);
    cast_bf16<<<512, 256, 0, stream>>>(proj_w, pwh, DIM * DIM, DIM * DIM / 4);

    qkv_mfma<<<dim3(49, 18), 256, 0, stream>>>(xh, wh, q_bf, k_bf, v_bf, vtb);
    attn_mfma<<<dim3(49, BHN, 2), 128, 0, stream>>>(q_bf, k_bf, vtb, o0, po1, pli);
    conv_pe<<<BHN * (NPATCH / 4), 256, 0, stream>>>(v_bf, conv_w, conv_b, pe);
    combine_att<<<2048, 256, 0, stream>>>(o0, po1, pli, pe, ah);
    proj_mfma<<<dim3(49, 6), 256, 0, stream>>>(ah, pwh, proj_b, out);
}